// Round 1
// baseline (487.233 us; speedup 1.0000x reference)
//
#include <hip/hip_runtime.h>

#define N_NODES 20000
#define DIM 128
#define N_EDGES 500000
#define BATCH 16384
#define EPS 1e-6f
#define L2E 1.4426950408889634f

typedef _Float16 half8 __attribute__((ext_vector_type(8)));
typedef _Float16 half4_t __attribute__((ext_vector_type(4)));
typedef float f32x4 __attribute__((ext_vector_type(4)));

__device__ __forceinline__ float fast_sqrtf(float x) {
#if __has_builtin(__builtin_amdgcn_sqrtf)
    return __builtin_amdgcn_sqrtf(x);
#else
    return sqrtf(x);
#endif
}
__device__ __forceinline__ float fast_exp2f(float x) {
#if __has_builtin(__builtin_amdgcn_exp2f)
    return __builtin_amdgcn_exp2f(x);
#else
    return exp2f(x);
#endif
}

#define NB_TILE 8256               // 129*64 wrapped-triangle 128x128 tiles

// ---- workspace layout (bytes) ----
#define OFF_PGEMM 0                // 8256*4 = 33024
#define OFF_PSH   33280            // A: gathered p_star rows fp16, chunk-swizzled (16384*128*2)
#define OFF_PPH   4227584          // B: gathered p rows fp16, chunk-swizzled
#define OFF_N2S   8421888
#define OFF_N2P   8487424
#define OFF_BPS   8552960          // L2E * beta_p_star gathered
#define OFF_BP    8618496          // L2E * beta_p gathered
#define OFF_END   8684032

// Prep: gather rows -> fp16 with per-row XOR chunk swizzle (so main can stage
// with linear global_load_lds and read conflict-free), + norms + L2E*beta.
// Physical 16B chunk pc within a row holds logical chunk lc where
// pc = (h<<3) | ((lc&7) ^ (row&7)), h = lc>>3 (K-half preserved).
__global__ __launch_bounds__(256) void prep_kernel(
    const float* __restrict__ p, const float* __restrict__ p_star,
    const float* __restrict__ beta_p, const float* __restrict__ beta_ps,
    const int* __restrict__ nodes_ps, const int* __restrict__ nodes_p,
    _Float16* __restrict__ Ah, float* __restrict__ n2A, float* __restrict__ bA2,
    _Float16* __restrict__ Bh, float* __restrict__ n2B, float* __restrict__ bB2)
{
    const int bx = blockIdx.x;
    const int g = threadIdx.x & 31;
    const int r8 = threadIdx.x >> 5;
    const bool isA = bx < 2048;
    const int row = (isA ? bx : bx - 2048) * 8 + r8;
    const int id = isA ? nodes_ps[row] : nodes_p[row];
    const float* src = isA ? p_star : p;
    float4 v = ((const float4*)(src + (size_t)id * DIM))[g];
    half4_t o;
    o[0] = (_Float16)v.x; o[1] = (_Float16)v.y; o[2] = (_Float16)v.z; o[3] = (_Float16)v.w;
    const int h = g >> 4;                      // K-half
    const int pc = ((g >> 1) & 7) ^ (row & 7); // swizzled in-half chunk
    _Float16* dst = isA ? Ah : Bh;
    *(half4_t*)(dst + (size_t)row * DIM + (((h << 3) | pc) << 3) + (g & 1) * 4) = o;
    float nrm = v.x * v.x + v.y * v.y + v.z * v.z + v.w * v.w;
    #pragma unroll
    for (int m = 16; m >= 1; m >>= 1) nrm += __shfl_xor(nrm, m, 32);
    if (g == 0) {
        if (isA) { n2A[row] = nrm; bA2[row] = L2E * beta_ps[id]; }
        else     { n2B[row] = nrm; bB2[row] = L2E * beta_p[id]; }
    }
}

// Stage one K-half (64 cols) of A and B tiles into LDS, linearly, via
// global_load_lds width-16. Each thread issues 2 chunks per array.
#define STAGE(h)                                                                   \
    {                                                                              \
        _Pragma("unroll")                                                          \
        for (int u = 0; u < 2; ++u) {                                              \
            const int cidx = w * 128 + u * 64 + lane;                              \
            const int row = cidx >> 3, cc = cidx & 7;                              \
            const int ldsoff = (w * 128 + u * 64) * 16;                            \
            __builtin_amdgcn_global_load_lds(                                      \
                (const __attribute__((address_space(1))) void*)(gA +               \
                    (((size_t)(i0 + row)) << 8) + ((h) << 7) + (cc << 4)),         \
                (__attribute__((address_space(3))) void*)(ldsA + ldsoff), 16, 0, 0); \
            __builtin_amdgcn_global_load_lds(                                      \
                (const __attribute__((address_space(1))) void*)(gB +               \
                    (((size_t)(j0 + row)) << 8) + ((h) << 7) + (cc << 4)),         \
                (__attribute__((address_space(3))) void*)(ldsB + ldsoff), 16, 0, 0); \
        }                                                                          \
    }

// One K-half of MFMA work (2 ksteps of K=32). Reads apply the XOR swizzle.
#define COMPUTE_HALF                                                               \
    if (cls != 2) {                                                                \
        _Pragma("unroll")                                                          \
        for (int ks = 0; ks < 2; ++ks) {                                           \
            const int lc = ks * 4 + quad;                                          \
            const int pcx = (lc ^ k7) << 3;                                        \
            half8 af[2], bf[4];                                                    \
            _Pragma("unroll")                                                      \
            for (int u = 0; u < 2; ++u)                                            \
                af[u] = *(const half8*)&As[(wm * 32 + u * 16 + lr) * 64 + pcx];    \
            _Pragma("unroll")                                                      \
            for (int v = 0; v < 4; ++v)                                            \
                bf[v] = *(const half8*)&Bs[(wn * 64 + v * 16 + lr) * 64 + pcx];    \
            _Pragma("unroll")                                                      \
            for (int mi = 0; mi < 2; ++mi)                                         \
                _Pragma("unroll")                                                  \
                for (int ni = 0; ni < 4; ++ni)                                     \
                    acc[mi][ni] = __builtin_amdgcn_mfma_f32_16x16x32_f16(          \
                        af[mi], bf[ni], acc[mi][ni], 0, 0, 0);                     \
        }                                                                          \
    }

// Main: 8256 blocks of 512 threads. One 128x128 non-link tile per block
// (8 waves x 32x64 subtile, K split in two 64-halves) + 64 link edges (fp32).
__global__ __launch_bounds__(512, 8) void main_kernel(
    const _Float16* __restrict__ Ag, const _Float16* __restrict__ Bg,
    const float* __restrict__ n2A, const float* __restrict__ n2B,
    const float* __restrict__ bA2, const float* __restrict__ bB2,
    const int* __restrict__ edges,
    const float* __restrict__ beta_p, const float* __restrict__ beta_ps,
    const float* __restrict__ pf, const float* __restrict__ psf,
    float* __restrict__ pgemm)
{
    const int bx = blockIdx.x, by = blockIdx.y;   // grid (129, 64)
    int ti, tj;
    const int len = 128 - by;
    if (bx < len) { ti = by; tj = by + bx; }
    else          { ti = 127 - by; tj = 127 - (bx - len); }
    const int i0 = ti * 128, j0 = tj * 128;
    const int bid = by * 129 + bx;
    const bool diag = (ti == tj);

    __shared__ __align__(16) _Float16 As[128 * 64];   // 16 KiB, unpadded (swizzled)
    __shared__ __align__(16) _Float16 Bs[128 * 64];   // 16 KiB
    __shared__ float smr[8];

    const int tid = threadIdx.x;
    const int lane = tid & 63;
    const int w = tid >> 6;       // 0..7
    const int wm = w & 3;         // 32-row quarter
    const int wn = w >> 2;        // 64-col half
    const int quad = lane >> 4;
    const int lr = lane & 15;
    const int k7 = lr & 7;        // read-side swizzle key (== row&7 of frag rows)

    auto* ldsA = (__attribute__((address_space(3))) char*)As;
    auto* ldsB = (__attribute__((address_space(3))) char*)Bs;
    const auto* gA = (const __attribute__((address_space(1))) char*)Ag;
    const auto* gB = (const __attribute__((address_space(1))) char*)Bg;

    // ---- link edges: fp32, exact reference math; loads issued up front ----
    float lsum = 0.f;
    f32x4 la0[2], la1[2], lb0[2], lb1[2];
    float eb2[2];
    bool ev[2];
    #pragma unroll
    for (int t = 0; t < 2; ++t) {
        int e = bid * 64 + w * 8 + quad * 2 + t;
        ev[t] = (e < N_EDGES);
        eb2[t] = 0.f;
        if (ev[t]) {
            int e0 = edges[e];
            int e1 = edges[N_EDGES + e];
            const float* ar = pf + (size_t)e0 * DIM + lr * 8;
            const float* br = psf + (size_t)e1 * DIM + lr * 8;
            la0[t] = *(const f32x4*)ar;       la1[t] = *(const f32x4*)(ar + 4);
            lb0[t] = *(const f32x4*)br;       lb1[t] = *(const f32x4*)(br + 4);
            if (lr == 0) eb2[t] = beta_ps[e0] + beta_p[e1];
        }
    }

    // ---- stage first K-half (async; overlaps link math below) ----
    STAGE(0)

    // ---- link math ----
    #pragma unroll
    for (int t = 0; t < 2; ++t) {
        if (ev[t]) {
            float s = 0.f;
            #pragma unroll
            for (int k = 0; k < 4; ++k) { float d = la0[t][k] - lb0[t][k] + EPS; s = fmaf(d, d, s); }
            #pragma unroll
            for (int k = 0; k < 4; ++k) { float d = la1[t][k] - lb1[t][k] + EPS; s = fmaf(d, d, s); }
            #pragma unroll
            for (int m = 8; m >= 1; m >>= 1) s += __shfl_xor(s, m, 16);
            if (lr == 0) lsum -= eb2[t] - fast_sqrtf(s);
        }
    }

    __syncthreads();   // staging h=0 complete (vmcnt drained by barrier)

    // wave class on diagonal tiles: rows [wm*32,+32) vs cols [wn*64,+64)
    int cls = 0;  // 0=free (all j>i), 1=masked, 2=dead
    if (diag) cls = (wn == 0) ? (wm >= 2 ? 2 : 1) : (wm >= 2 ? 1 : 0);

    f32x4 acc[2][4] = {};

    COMPUTE_HALF
    __syncthreads();   // WAR: all reads of half 0 done before restage
    STAGE(1)
    __syncthreads();   // staging h=1 complete
    COMPUTE_HALF

    // ---- epilogue ----
    const int ilo = i0 + wm * 32, jlo = j0 + wn * 64;
    if (cls != 2) {
        f32x4 n2i[2], bi[2];
        #pragma unroll
        for (int mi = 0; mi < 2; ++mi) {
            n2i[mi] = *(const f32x4*)&n2A[ilo + mi * 16 + quad * 4];
            bi[mi]  = *(const f32x4*)&bA2[ilo + mi * 16 + quad * 4];
        }
        float n2j[4], bj[4];
        #pragma unroll
        for (int ni = 0; ni < 4; ++ni) {
            n2j[ni] = n2B[jlo + ni * 16 + lr];
            bj[ni]  = bB2[jlo + ni * 16 + lr];
        }

        // C/D layout: col = lane&15, row = quad*4 + reg
        if (cls == 0) {
            #pragma unroll
            for (int mi = 0; mi < 2; ++mi)
                #pragma unroll
                for (int ni = 0; ni < 4; ++ni) {
                    f32x4 d = acc[mi][ni];
                    #pragma unroll
                    for (int r = 0; r < 4; ++r) {
                        float tt = n2i[mi][r] + n2j[ni];
                        float sq = fmaxf(fmaf(d[r], -2.f, tt), 0.f);
                        float arg = fmaf(fast_sqrtf(sq), -L2E, bi[mi][r] + bj[ni]);
                        lsum += fast_exp2f(arg);
                    }
                }
        } else {
            #pragma unroll
            for (int mi = 0; mi < 2; ++mi)
                #pragma unroll
                for (int ni = 0; ni < 4; ++ni) {
                    f32x4 d = acc[mi][ni];
                    #pragma unroll
                    for (int r = 0; r < 4; ++r) {
                        int ig = ilo + mi * 16 + quad * 4 + r;
                        int jg = jlo + ni * 16 + lr;
                        float tt = n2i[mi][r] + n2j[ni];
                        float sq = fmaxf(fmaf(d[r], -2.f, tt), 0.f);
                        float arg = fmaf(fast_sqrtf(sq), -L2E, bi[mi][r] + bj[ni]);
                        float ex = fast_exp2f(arg);
                        if (jg > ig) lsum += ex;
                    }
                }
        }
    }

    #pragma unroll
    for (int m = 32; m >= 1; m >>= 1) lsum += __shfl_xor(lsum, m, 64);
    if (lane == 0) smr[w] = lsum;
    __syncthreads();
    if (tid == 0) {
        float t = 0.f;
        #pragma unroll
        for (int i = 0; i < 8; ++i) t += smr[i];
        pgemm[bid] = t;
    }
}

// single-block final reduction over 8256 partials
__global__ __launch_bounds__(1024) void reduce_kernel(
    const float* __restrict__ pg, float* __restrict__ out)
{
    float s = 0.f;
    for (int k = threadIdx.x; k < NB_TILE; k += 1024) s += pg[k];
    #pragma unroll
    for (int m = 32; m >= 1; m >>= 1) s += __shfl_xor(s, m, 64);
    __shared__ float sm[16];
    if ((threadIdx.x & 63) == 0) sm[threadIdx.x >> 6] = s;
    __syncthreads();
    if (threadIdx.x == 0) {
        float t = 0.f;
        #pragma unroll
        for (int i = 0; i < 16; ++i) t += sm[i];
        out[0] = t;
    }
}

extern "C" void kernel_launch(void* const* d_in, const int* in_sizes, int n_in,
                              void* d_out, int out_size, void* d_ws, size_t ws_size,
                              hipStream_t stream) {
    const int* edges = (const int*)d_in[0];
    const int* nodes_p_star = (const int*)d_in[1];
    const int* nodes_p = (const int*)d_in[2];
    const float* beta_p = (const float*)d_in[3];
    const float* beta_p_star = (const float*)d_in[4];
    const float* p = (const float*)d_in[5];
    const float* p_star = (const float*)d_in[6];

    char* ws = (char*)d_ws;
    float* pgemm = (float*)(ws + OFF_PGEMM);
    _Float16* psh = (_Float16*)(ws + OFF_PSH);
    _Float16* pph = (_Float16*)(ws + OFF_PPH);
    float* n2s = (float*)(ws + OFF_N2S);
    float* n2p = (float*)(ws + OFF_N2P);
    float* bps2 = (float*)(ws + OFF_BPS);
    float* bp2 = (float*)(ws + OFF_BP);

    prep_kernel<<<4096, 256, 0, stream>>>(
        p, p_star, beta_p, beta_p_star, nodes_p_star, nodes_p,
        psh, n2s, bps2, pph, n2p, bp2);

    main_kernel<<<dim3(129, 64), 512, 0, stream>>>(
        psh, pph, n2s, n2p, bps2, bp2,
        edges, beta_p, beta_p_star, p, p_star,
        pgemm);

    reduce_kernel<<<1, 1024, 0, stream>>>(pgemm, (float*)d_out);
}

// Round 2
// 298.106 us; speedup vs baseline: 1.6344x; 1.6344x over previous
//
#include <hip/hip_runtime.h>

#define N_NODES 20000
#define DIM 128
#define N_EDGES 500000
#define BATCH 16384
#define EPS 1e-6f
#define L2E 1.4426950408889634f

typedef _Float16 half8 __attribute__((ext_vector_type(8)));
typedef _Float16 half4_t __attribute__((ext_vector_type(4)));
typedef float f32x4 __attribute__((ext_vector_type(4)));

__device__ __forceinline__ float fast_sqrtf(float x) {
#if __has_builtin(__builtin_amdgcn_sqrtf)
    return __builtin_amdgcn_sqrtf(x);
#else
    return sqrtf(x);
#endif
}
__device__ __forceinline__ float fast_exp2f(float x) {
#if __has_builtin(__builtin_amdgcn_exp2f)
    return __builtin_amdgcn_exp2f(x);
#else
    return exp2f(x);
#endif
}

#define NB_TILE 8256               // 129*64 wrapped-triangle 128x128 tiles

// ---- workspace layout (bytes) ----
#define OFF_PGEMM 0                // 8256*4 = 33024
#define OFF_PSH   33280            // A: gathered p_star rows fp16, chunk-swizzled (16384*128*2)
#define OFF_PPH   4227584          // B: gathered p rows fp16, chunk-swizzled
#define OFF_N2S   8421888
#define OFF_N2P   8487424
#define OFF_BPS   8552960          // L2E * beta_p_star gathered
#define OFF_BP    8618496          // L2E * beta_p gathered
#define OFF_END   8684032

// Prep: gather rows -> fp16 with per-row XOR chunk swizzle (so main can stage
// with linear global_load_lds and read conflict-free), + norms + L2E*beta.
// Physical 16B chunk pc within a row holds logical chunk lc where
// pc = (h<<3) | ((lc&7) ^ (row&7)), h = lc>>3 (K-half preserved).
__global__ __launch_bounds__(256) void prep_kernel(
    const float* __restrict__ p, const float* __restrict__ p_star,
    const float* __restrict__ beta_p, const float* __restrict__ beta_ps,
    const int* __restrict__ nodes_ps, const int* __restrict__ nodes_p,
    _Float16* __restrict__ Ah, float* __restrict__ n2A, float* __restrict__ bA2,
    _Float16* __restrict__ Bh, float* __restrict__ n2B, float* __restrict__ bB2)
{
    const int bx = blockIdx.x;
    const int g = threadIdx.x & 31;
    const int r8 = threadIdx.x >> 5;
    const bool isA = bx < 2048;
    const int row = (isA ? bx : bx - 2048) * 8 + r8;
    const int id = isA ? nodes_ps[row] : nodes_p[row];
    const float* src = isA ? p_star : p;
    float4 v = ((const float4*)(src + (size_t)id * DIM))[g];
    half4_t o;
    o[0] = (_Float16)v.x; o[1] = (_Float16)v.y; o[2] = (_Float16)v.z; o[3] = (_Float16)v.w;
    const int h = g >> 4;                      // K-half
    const int pc = ((g >> 1) & 7) ^ (row & 7); // swizzled in-half chunk
    _Float16* dst = isA ? Ah : Bh;
    *(half4_t*)(dst + (size_t)row * DIM + (((h << 3) | pc) << 3) + (g & 1) * 4) = o;
    float nrm = v.x * v.x + v.y * v.y + v.z * v.z + v.w * v.w;
    #pragma unroll
    for (int m = 16; m >= 1; m >>= 1) nrm += __shfl_xor(nrm, m, 32);
    if (g == 0) {
        if (isA) { n2A[row] = nrm; bA2[row] = L2E * beta_ps[id]; }
        else     { n2B[row] = nrm; bB2[row] = L2E * beta_p[id]; }
    }
}

// Stage one K-half (64 cols) of A and B tiles into LDS, linearly, via
// global_load_lds width-16. Each thread issues 2 chunks per array.
#define STAGE(h)                                                                   \
    {                                                                              \
        _Pragma("unroll")                                                          \
        for (int u = 0; u < 2; ++u) {                                              \
            const int cidx = w * 128 + u * 64 + lane;                              \
            const int row = cidx >> 3, cc = cidx & 7;                              \
            const int ldsoff = (w * 128 + u * 64) * 16;                            \
            __builtin_amdgcn_global_load_lds(                                      \
                (const __attribute__((address_space(1))) void*)(gA +               \
                    (((size_t)(i0 + row)) << 8) + ((h) << 7) + (cc << 4)),         \
                (__attribute__((address_space(3))) void*)(ldsA + ldsoff), 16, 0, 0); \
            __builtin_amdgcn_global_load_lds(                                      \
                (const __attribute__((address_space(1))) void*)(gB +               \
                    (((size_t)(j0 + row)) << 8) + ((h) << 7) + (cc << 4)),         \
                (__attribute__((address_space(3))) void*)(ldsB + ldsoff), 16, 0, 0); \
        }                                                                          \
    }

// One K-half of MFMA work (2 ksteps of K=32). Reads apply the XOR swizzle.
#define COMPUTE_HALF                                                               \
    if (cls != 2) {                                                                \
        _Pragma("unroll")                                                          \
        for (int ks = 0; ks < 2; ++ks) {                                           \
            const int lc = ks * 4 + quad;                                          \
            const int pcx = (lc ^ k7) << 3;                                        \
            half8 af[2], bf[4];                                                    \
            _Pragma("unroll")                                                      \
            for (int u = 0; u < 2; ++u)                                            \
                af[u] = *(const half8*)&As[(wm * 32 + u * 16 + lr) * 64 + pcx];    \
            _Pragma("unroll")                                                      \
            for (int v = 0; v < 4; ++v)                                            \
                bf[v] = *(const half8*)&Bs[(wn * 64 + v * 16 + lr) * 64 + pcx];    \
            _Pragma("unroll")                                                      \
            for (int mi = 0; mi < 2; ++mi)                                         \
                _Pragma("unroll")                                                  \
                for (int ni = 0; ni < 4; ++ni)                                     \
                    acc[mi][ni] = __builtin_amdgcn_mfma_f32_16x16x32_f16(          \
                        af[mi], bf[ni], acc[mi][ni], 0, 0, 0);                     \
        }                                                                          \
    }

// Main: 8256 blocks of 512 threads. One 128x128 non-link tile per block
// (8 waves x 32x64 subtile, K split in two 64-halves) + 64 link edges (fp32).
__global__ __launch_bounds__(512, 6) void main_kernel(
    const _Float16* __restrict__ Ag, const _Float16* __restrict__ Bg,
    const float* __restrict__ n2A, const float* __restrict__ n2B,
    const float* __restrict__ bA2, const float* __restrict__ bB2,
    const int* __restrict__ edges,
    const float* __restrict__ beta_p, const float* __restrict__ beta_ps,
    const float* __restrict__ pf, const float* __restrict__ psf,
    float* __restrict__ pgemm)
{
    const int bx = blockIdx.x, by = blockIdx.y;   // grid (129, 64)
    int ti, tj;
    const int len = 128 - by;
    if (bx < len) { ti = by; tj = by + bx; }
    else          { ti = 127 - by; tj = 127 - (bx - len); }
    const int i0 = ti * 128, j0 = tj * 128;
    const int bid = by * 129 + bx;
    const bool diag = (ti == tj);

    __shared__ __align__(16) _Float16 As[128 * 64];   // 16 KiB, unpadded (swizzled)
    __shared__ __align__(16) _Float16 Bs[128 * 64];   // 16 KiB
    __shared__ float smr[8];

    const int tid = threadIdx.x;
    const int lane = tid & 63;
    const int w = tid >> 6;       // 0..7
    const int wm = w & 3;         // 32-row quarter
    const int wn = w >> 2;        // 64-col half
    const int quad = lane >> 4;
    const int lr = lane & 15;
    const int k7 = lr & 7;        // read-side swizzle key (== row&7 of frag rows)

    auto* ldsA = (__attribute__((address_space(3))) char*)As;
    auto* ldsB = (__attribute__((address_space(3))) char*)Bs;
    const auto* gA = (const __attribute__((address_space(1))) char*)Ag;
    const auto* gB = (const __attribute__((address_space(1))) char*)Bg;

    // ---- stage first K-half (async; overlaps link math below) ----
    STAGE(0)

    // ---- link edges: fp32, exact reference math, transient live range ----
    float lsum = 0.f;
    #pragma unroll
    for (int t = 0; t < 2; ++t) {
        int e = bid * 64 + w * 8 + quad * 2 + t;
        if (e < N_EDGES) {
            int e0 = edges[e];
            int e1 = edges[N_EDGES + e];
            const float* ar = pf + (size_t)e0 * DIM + lr * 8;
            const float* br = psf + (size_t)e1 * DIM + lr * 8;
            f32x4 a0 = *(const f32x4*)ar;       f32x4 a1 = *(const f32x4*)(ar + 4);
            f32x4 b0 = *(const f32x4*)br;       f32x4 b1 = *(const f32x4*)(br + 4);
            float eb2 = (lr == 0) ? (beta_ps[e0] + beta_p[e1]) : 0.f;
            float s = 0.f;
            #pragma unroll
            for (int k = 0; k < 4; ++k) { float d = a0[k] - b0[k] + EPS; s = fmaf(d, d, s); }
            #pragma unroll
            for (int k = 0; k < 4; ++k) { float d = a1[k] - b1[k] + EPS; s = fmaf(d, d, s); }
            #pragma unroll
            for (int m = 8; m >= 1; m >>= 1) s += __shfl_xor(s, m, 16);
            if (lr == 0) lsum -= eb2 - fast_sqrtf(s);
        }
    }

    __syncthreads();   // staging h=0 complete (vmcnt drained by barrier)

    // wave class on diagonal tiles: rows [wm*32,+32) vs cols [wn*64,+64)
    int cls = 0;  // 0=free (all j>i), 1=masked, 2=dead
    if (diag) cls = (wn == 0) ? (wm >= 2 ? 2 : 1) : (wm >= 2 ? 1 : 0);

    f32x4 acc[2][4] = {};

    COMPUTE_HALF
    __syncthreads();   // WAR: all reads of half 0 done before restage
    STAGE(1)
    __syncthreads();   // staging h=1 complete
    COMPUTE_HALF

    // ---- epilogue ----
    const int ilo = i0 + wm * 32, jlo = j0 + wn * 64;
    if (cls != 2) {
        f32x4 n2i[2], bi[2];
        #pragma unroll
        for (int mi = 0; mi < 2; ++mi) {
            n2i[mi] = *(const f32x4*)&n2A[ilo + mi * 16 + quad * 4];
            bi[mi]  = *(const f32x4*)&bA2[ilo + mi * 16 + quad * 4];
        }
        float n2j[4], bj[4];
        #pragma unroll
        for (int ni = 0; ni < 4; ++ni) {
            n2j[ni] = n2B[jlo + ni * 16 + lr];
            bj[ni]  = bB2[jlo + ni * 16 + lr];
        }

        // C/D layout: col = lane&15, row = quad*4 + reg
        if (cls == 0) {
            #pragma unroll
            for (int mi = 0; mi < 2; ++mi)
                #pragma unroll
                for (int ni = 0; ni < 4; ++ni) {
                    f32x4 d = acc[mi][ni];
                    #pragma unroll
                    for (int r = 0; r < 4; ++r) {
                        float tt = n2i[mi][r] + n2j[ni];
                        float sq = fmaxf(fmaf(d[r], -2.f, tt), 0.f);
                        float arg = fmaf(fast_sqrtf(sq), -L2E, bi[mi][r] + bj[ni]);
                        lsum += fast_exp2f(arg);
                    }
                }
        } else {
            #pragma unroll
            for (int mi = 0; mi < 2; ++mi)
                #pragma unroll
                for (int ni = 0; ni < 4; ++ni) {
                    f32x4 d = acc[mi][ni];
                    #pragma unroll
                    for (int r = 0; r < 4; ++r) {
                        int ig = ilo + mi * 16 + quad * 4 + r;
                        int jg = jlo + ni * 16 + lr;
                        float tt = n2i[mi][r] + n2j[ni];
                        float sq = fmaxf(fmaf(d[r], -2.f, tt), 0.f);
                        float arg = fmaf(fast_sqrtf(sq), -L2E, bi[mi][r] + bj[ni]);
                        float ex = fast_exp2f(arg);
                        if (jg > ig) lsum += ex;
                    }
                }
        }
    }

    #pragma unroll
    for (int m = 32; m >= 1; m >>= 1) lsum += __shfl_xor(lsum, m, 64);
    if (lane == 0) smr[w] = lsum;
    __syncthreads();
    if (tid == 0) {
        float t = 0.f;
        #pragma unroll
        for (int i = 0; i < 8; ++i) t += smr[i];
        pgemm[bid] = t;
    }
}

// single-block final reduction over 8256 partials
__global__ __launch_bounds__(1024) void reduce_kernel(
    const float* __restrict__ pg, float* __restrict__ out)
{
    float s = 0.f;
    for (int k = threadIdx.x; k < NB_TILE; k += 1024) s += pg[k];
    #pragma unroll
    for (int m = 32; m >= 1; m >>= 1) s += __shfl_xor(s, m, 64);
    __shared__ float sm[16];
    if ((threadIdx.x & 63) == 0) sm[threadIdx.x >> 6] = s;
    __syncthreads();
    if (threadIdx.x == 0) {
        float t = 0.f;
        #pragma unroll
        for (int i = 0; i < 16; ++i) t += sm[i];
        out[0] = t;
    }
}

extern "C" void kernel_launch(void* const* d_in, const int* in_sizes, int n_in,
                              void* d_out, int out_size, void* d_ws, size_t ws_size,
                              hipStream_t stream) {
    const int* edges = (const int*)d_in[0];
    const int* nodes_p_star = (const int*)d_in[1];
    const int* nodes_p = (const int*)d_in[2];
    const float* beta_p = (const float*)d_in[3];
    const float* beta_p_star = (const float*)d_in[4];
    const float* p = (const float*)d_in[5];
    const float* p_star = (const float*)d_in[6];

    char* ws = (char*)d_ws;
    float* pgemm = (float*)(ws + OFF_PGEMM);
    _Float16* psh = (_Float16*)(ws + OFF_PSH);
    _Float16* pph = (_Float16*)(ws + OFF_PPH);
    float* n2s = (float*)(ws + OFF_N2S);
    float* n2p = (float*)(ws + OFF_N2P);
    float* bps2 = (float*)(ws + OFF_BPS);
    float* bp2 = (float*)(ws + OFF_BP);

    prep_kernel<<<4096, 256, 0, stream>>>(
        p, p_star, beta_p, beta_p_star, nodes_p_star, nodes_p,
        psh, n2s, bps2, pph, n2p, bp2);

    main_kernel<<<dim3(129, 64), 512, 0, stream>>>(
        psh, pph, n2s, n2p, bps2, bp2,
        edges, beta_p, beta_p_star, p, p_star,
        pgemm);

    reduce_kernel<<<1, 1024, 0, stream>>>(pgemm, (float*)d_out);
}

// Round 3
// 205.742 us; speedup vs baseline: 2.3682x; 1.4489x over previous
//
#include <hip/hip_runtime.h>

#define N_NODES 20000
#define DIM 128
#define N_EDGES 500000
#define BATCH 16384
#define EPS 1e-6f
#define L2E 1.4426950408889634f

typedef _Float16 half8 __attribute__((ext_vector_type(8)));
typedef _Float16 half4_t __attribute__((ext_vector_type(4)));
typedef float f32x4 __attribute__((ext_vector_type(4)));

__device__ __forceinline__ float fast_sqrtf(float x) {
#if __has_builtin(__builtin_amdgcn_sqrtf)
    return __builtin_amdgcn_sqrtf(x);
#else
    return sqrtf(x);
#endif
}
__device__ __forceinline__ float fast_exp2f(float x) {
#if __has_builtin(__builtin_amdgcn_exp2f)
    return __builtin_amdgcn_exp2f(x);
#else
    return exp2f(x);
#endif
}

#define NB_TILE 8256               // 129*64 wrapped-triangle 128x128 tiles

// ---- workspace layout (bytes) ----
#define OFF_PGEMM 0                // 8256*4 = 33024
#define OFF_PSH   33280            // A: gathered p_star rows fp16, chunk-swizzled (16384*128*2)
#define OFF_PPH   4227584          // B: gathered p rows fp16, chunk-swizzled
#define OFF_N2S   8421888
#define OFF_N2P   8487424
#define OFF_BPS   8552960          // L2E * beta_p_star gathered
#define OFF_BP    8618496          // L2E * beta_p gathered
#define OFF_END   8684032

// Prep: gather rows -> fp16 with per-row XOR chunk swizzle (so main can stage
// with linear global_load_lds and read conflict-free), + norms + L2E*beta.
// Physical 16B chunk pc within a row holds logical chunk lc where
// pc = (h<<3) | ((lc&7) ^ (row&7)), h = lc>>3 (K-half preserved).
__global__ __launch_bounds__(256) void prep_kernel(
    const float* __restrict__ p, const float* __restrict__ p_star,
    const float* __restrict__ beta_p, const float* __restrict__ beta_ps,
    const int* __restrict__ nodes_ps, const int* __restrict__ nodes_p,
    _Float16* __restrict__ Ah, float* __restrict__ n2A, float* __restrict__ bA2,
    _Float16* __restrict__ Bh, float* __restrict__ n2B, float* __restrict__ bB2)
{
    const int bx = blockIdx.x;
    const int g = threadIdx.x & 31;
    const int r8 = threadIdx.x >> 5;
    const bool isA = bx < 2048;
    const int row = (isA ? bx : bx - 2048) * 8 + r8;
    const int id = isA ? nodes_ps[row] : nodes_p[row];
    const float* src = isA ? p_star : p;
    float4 v = ((const float4*)(src + (size_t)id * DIM))[g];
    half4_t o;
    o[0] = (_Float16)v.x; o[1] = (_Float16)v.y; o[2] = (_Float16)v.z; o[3] = (_Float16)v.w;
    const int h = g >> 4;                      // K-half
    const int pc = ((g >> 1) & 7) ^ (row & 7); // swizzled in-half chunk
    _Float16* dst = isA ? Ah : Bh;
    *(half4_t*)(dst + (size_t)row * DIM + (((h << 3) | pc) << 3) + (g & 1) * 4) = o;
    float nrm = v.x * v.x + v.y * v.y + v.z * v.z + v.w * v.w;
    #pragma unroll
    for (int m = 16; m >= 1; m >>= 1) nrm += __shfl_xor(nrm, m, 32);
    if (g == 0) {
        if (isA) { n2A[row] = nrm; bA2[row] = L2E * beta_ps[id]; }
        else     { n2B[row] = nrm; bB2[row] = L2E * beta_p[id]; }
    }
}

// Stage one K-half (64 cols) of A and B tiles into LDS, linearly, via
// global_load_lds width-16. Each thread issues 2 chunks per array.
#define STAGE(h)                                                                   \
    {                                                                              \
        _Pragma("unroll")                                                          \
        for (int u = 0; u < 2; ++u) {                                              \
            const int cidx = w * 128 + u * 64 + lane;                              \
            const int row = cidx >> 3, cc = cidx & 7;                              \
            const int ldsoff = (w * 128 + u * 64) * 16;                            \
            __builtin_amdgcn_global_load_lds(                                      \
                (const __attribute__((address_space(1))) void*)(gA +               \
                    (((size_t)(i0 + row)) << 8) + ((h) << 7) + (cc << 4)),         \
                (__attribute__((address_space(3))) void*)(ldsA + ldsoff), 16, 0, 0); \
            __builtin_amdgcn_global_load_lds(                                      \
                (const __attribute__((address_space(1))) void*)(gB +               \
                    (((size_t)(j0 + row)) << 8) + ((h) << 7) + (cc << 4)),         \
                (__attribute__((address_space(3))) void*)(ldsB + ldsoff), 16, 0, 0); \
        }                                                                          \
    }

// One K-half of MFMA work (2 ksteps of K=32). Reads apply the XOR swizzle.
#define COMPUTE_HALF                                                               \
    if (cls != 2) {                                                                \
        _Pragma("unroll")                                                          \
        for (int ks = 0; ks < 2; ++ks) {                                           \
            const int lc = ks * 4 + quad;                                          \
            const int pcx = (lc ^ k7) << 3;                                        \
            half8 af[2], bf[4];                                                    \
            _Pragma("unroll")                                                      \
            for (int u = 0; u < 2; ++u)                                            \
                af[u] = *(const half8*)&As[(wm * 32 + u * 16 + lr) * 64 + pcx];    \
            _Pragma("unroll")                                                      \
            for (int v = 0; v < 4; ++v)                                            \
                bf[v] = *(const half8*)&Bs[(wn * 64 + v * 16 + lr) * 64 + pcx];    \
            _Pragma("unroll")                                                      \
            for (int mi = 0; mi < 2; ++mi)                                         \
                _Pragma("unroll")                                                  \
                for (int ni = 0; ni < 4; ++ni)                                     \
                    acc[mi][ni] = __builtin_amdgcn_mfma_f32_16x16x32_f16(          \
                        af[mi], bf[ni], acc[mi][ni], 0, 0, 0);                     \
        }                                                                          \
    }

// Main: 8256 blocks of 512 threads. One 128x128 non-link tile per block
// (8 waves x 32x64 subtile, K split in two 64-halves) + 64 link edges (fp32).
// launch_bounds(512,4): cap 128 regs — proven spill-free regime (round 0).
// The floor does not limit achieved occupancy if the allocator lands lower.
__global__ __launch_bounds__(512, 4) void main_kernel(
    const _Float16* __restrict__ Ag, const _Float16* __restrict__ Bg,
    const float* __restrict__ n2A, const float* __restrict__ n2B,
    const float* __restrict__ bA2, const float* __restrict__ bB2,
    const int* __restrict__ edges,
    const float* __restrict__ beta_p, const float* __restrict__ beta_ps,
    const float* __restrict__ pf, const float* __restrict__ psf,
    float* __restrict__ pgemm)
{
    const int bx = blockIdx.x, by = blockIdx.y;   // grid (129, 64)
    int ti, tj;
    const int len = 128 - by;
    if (bx < len) { ti = by; tj = by + bx; }
    else          { ti = 127 - by; tj = 127 - (bx - len); }
    const int i0 = ti * 128, j0 = tj * 128;
    const int bid = by * 129 + bx;
    const bool diag = (ti == tj);

    __shared__ __align__(16) _Float16 As[128 * 64];   // 16 KiB, unpadded (swizzled)
    __shared__ __align__(16) _Float16 Bs[128 * 64];   // 16 KiB
    __shared__ float smr[8];

    const int tid = threadIdx.x;
    const int lane = tid & 63;
    const int w = tid >> 6;       // 0..7
    const int wm = w & 3;         // 32-row quarter
    const int wn = w >> 2;        // 64-col half
    const int quad = lane >> 4;
    const int lr = lane & 15;
    const int k7 = lr & 7;        // read-side swizzle key (== row&7 of frag rows)

    auto* ldsA = (__attribute__((address_space(3))) char*)As;
    auto* ldsB = (__attribute__((address_space(3))) char*)Bs;
    const auto* gA = (const __attribute__((address_space(1))) char*)Ag;
    const auto* gB = (const __attribute__((address_space(1))) char*)Bg;

    // ---- stage first K-half (async; overlaps link math below) ----
    STAGE(0)

    // ---- link edges: fp32, exact reference math, transient live range ----
    float lsum = 0.f;
    #pragma unroll
    for (int t = 0; t < 2; ++t) {
        int e = bid * 64 + w * 8 + quad * 2 + t;
        if (e < N_EDGES) {
            int e0 = edges[e];
            int e1 = edges[N_EDGES + e];
            const float* ar = pf + (size_t)e0 * DIM + lr * 8;
            const float* br = psf + (size_t)e1 * DIM + lr * 8;
            f32x4 a0 = *(const f32x4*)ar;       f32x4 a1 = *(const f32x4*)(ar + 4);
            f32x4 b0 = *(const f32x4*)br;       f32x4 b1 = *(const f32x4*)(br + 4);
            float eb2 = (lr == 0) ? (beta_ps[e0] + beta_p[e1]) : 0.f;
            float s = 0.f;
            #pragma unroll
            for (int k = 0; k < 4; ++k) { float d = a0[k] - b0[k] + EPS; s = fmaf(d, d, s); }
            #pragma unroll
            for (int k = 0; k < 4; ++k) { float d = a1[k] - b1[k] + EPS; s = fmaf(d, d, s); }
            #pragma unroll
            for (int m = 8; m >= 1; m >>= 1) s += __shfl_xor(s, m, 16);
            if (lr == 0) lsum -= eb2 - fast_sqrtf(s);
        }
    }

    __syncthreads();   // staging h=0 complete (vmcnt drained by barrier)

    // wave class on diagonal tiles: rows [wm*32,+32) vs cols [wn*64,+64)
    int cls = 0;  // 0=free (all j>i), 1=masked, 2=dead
    if (diag) cls = (wn == 0) ? (wm >= 2 ? 2 : 1) : (wm >= 2 ? 1 : 0);

    f32x4 acc[2][4] = {};

    COMPUTE_HALF
    __syncthreads();   // WAR: all reads of half 0 done before restage
    STAGE(1)
    __syncthreads();   // staging h=1 complete
    COMPUTE_HALF

    // ---- epilogue ----
    const int ilo = i0 + wm * 32, jlo = j0 + wn * 64;
    if (cls != 2) {
        f32x4 n2i[2], bi[2];
        #pragma unroll
        for (int mi = 0; mi < 2; ++mi) {
            n2i[mi] = *(const f32x4*)&n2A[ilo + mi * 16 + quad * 4];
            bi[mi]  = *(const f32x4*)&bA2[ilo + mi * 16 + quad * 4];
        }
        float n2j[4], bj[4];
        #pragma unroll
        for (int ni = 0; ni < 4; ++ni) {
            n2j[ni] = n2B[jlo + ni * 16 + lr];
            bj[ni]  = bB2[jlo + ni * 16 + lr];
        }

        // C/D layout: col = lane&15, row = quad*4 + reg
        if (cls == 0) {
            #pragma unroll
            for (int mi = 0; mi < 2; ++mi)
                #pragma unroll
                for (int ni = 0; ni < 4; ++ni) {
                    f32x4 d = acc[mi][ni];
                    #pragma unroll
                    for (int r = 0; r < 4; ++r) {
                        float tt = n2i[mi][r] + n2j[ni];
                        float sq = fmaxf(fmaf(d[r], -2.f, tt), 0.f);
                        float arg = fmaf(fast_sqrtf(sq), -L2E, bi[mi][r] + bj[ni]);
                        lsum += fast_exp2f(arg);
                    }
                }
        } else {
            #pragma unroll
            for (int mi = 0; mi < 2; ++mi)
                #pragma unroll
                for (int ni = 0; ni < 4; ++ni) {
                    f32x4 d = acc[mi][ni];
                    #pragma unroll
                    for (int r = 0; r < 4; ++r) {
                        int ig = ilo + mi * 16 + quad * 4 + r;
                        int jg = jlo + ni * 16 + lr;
                        float tt = n2i[mi][r] + n2j[ni];
                        float sq = fmaxf(fmaf(d[r], -2.f, tt), 0.f);
                        float arg = fmaf(fast_sqrtf(sq), -L2E, bi[mi][r] + bj[ni]);
                        float ex = fast_exp2f(arg);
                        if (jg > ig) lsum += ex;
                    }
                }
        }
    }

    #pragma unroll
    for (int m = 32; m >= 1; m >>= 1) lsum += __shfl_xor(lsum, m, 64);
    if (lane == 0) smr[w] = lsum;
    __syncthreads();
    if (tid == 0) {
        float t = 0.f;
        #pragma unroll
        for (int i = 0; i < 8; ++i) t += smr[i];
        pgemm[bid] = t;
    }
}

// single-block final reduction over 8256 partials
__global__ __launch_bounds__(1024) void reduce_kernel(
    const float* __restrict__ pg, float* __restrict__ out)
{
    float s = 0.f;
    for (int k = threadIdx.x; k < NB_TILE; k += 1024) s += pg[k];
    #pragma unroll
    for (int m = 32; m >= 1; m >>= 1) s += __shfl_xor(s, m, 64);
    __shared__ float sm[16];
    if ((threadIdx.x & 63) == 0) sm[threadIdx.x >> 6] = s;
    __syncthreads();
    if (threadIdx.x == 0) {
        float t = 0.f;
        #pragma unroll
        for (int i = 0; i < 16; ++i) t += sm[i];
        out[0] = t;
    }
}

extern "C" void kernel_launch(void* const* d_in, const int* in_sizes, int n_in,
                              void* d_out, int out_size, void* d_ws, size_t ws_size,
                              hipStream_t stream) {
    const int* edges = (const int*)d_in[0];
    const int* nodes_p_star = (const int*)d_in[1];
    const int* nodes_p = (const int*)d_in[2];
    const float* beta_p = (const float*)d_in[3];
    const float* beta_p_star = (const float*)d_in[4];
    const float* p = (const float*)d_in[5];
    const float* p_star = (const float*)d_in[6];

    char* ws = (char*)d_ws;
    float* pgemm = (float*)(ws + OFF_PGEMM);
    _Float16* psh = (_Float16*)(ws + OFF_PSH);
    _Float16* pph = (_Float16*)(ws + OFF_PPH);
    float* n2s = (float*)(ws + OFF_N2S);
    float* n2p = (float*)(ws + OFF_N2P);
    float* bps2 = (float*)(ws + OFF_BPS);
    float* bp2 = (float*)(ws + OFF_BP);

    prep_kernel<<<4096, 256, 0, stream>>>(
        p, p_star, beta_p, beta_p_star, nodes_p_star, nodes_p,
        psh, n2s, bps2, pph, n2p, bp2);

    main_kernel<<<dim3(129, 64), 512, 0, stream>>>(
        psh, pph, n2s, n2p, bps2, bp2,
        edges, beta_p, beta_p_star, p, p_star,
        pgemm);

    reduce_kernel<<<1, 1024, 0, stream>>>(pgemm, (float*)d_out);
}

// Round 4
// 193.344 us; speedup vs baseline: 2.5200x; 1.0641x over previous
//
#include <hip/hip_runtime.h>

#define N_NODES 20000
#define DIM 128
#define N_EDGES 500000
#define BATCH 16384
#define EPS 1e-6f
#define L2E 1.4426950408889634f

typedef _Float16 half8 __attribute__((ext_vector_type(8)));
typedef _Float16 half4_t __attribute__((ext_vector_type(4)));
typedef float f32x4 __attribute__((ext_vector_type(4)));

__device__ __forceinline__ float fast_sqrtf(float x) {
#if __has_builtin(__builtin_amdgcn_sqrtf)
    return __builtin_amdgcn_sqrtf(x);
#else
    return sqrtf(x);
#endif
}
__device__ __forceinline__ float fast_exp2f(float x) {
#if __has_builtin(__builtin_amdgcn_exp2f)
    return __builtin_amdgcn_exp2f(x);
#else
    return exp2f(x);
#endif
}

#define NB_TILE 8256               // 129*64 wrapped-triangle 128x128 tiles
#define N_BLK   512                // persistent blocks; tiles strided by N_BLK

// ---- workspace layout (bytes) ----
#define OFF_PGEMM 0                // N_BLK*4
#define OFF_PSH   33280            // A: gathered p_star rows fp16, chunk-swizzled (16384*128*2)
#define OFF_PPH   4227584          // B: gathered p rows fp16, chunk-swizzled
#define OFF_N2S   8421888
#define OFF_N2P   8487424
#define OFF_BPS   8552960          // L2E * beta_p_star gathered
#define OFF_BP    8618496          // L2E * beta_p gathered
#define OFF_END   8684032

// Prep: gather rows -> fp16 with per-row XOR chunk swizzle (so main can stage
// with linear global_load_lds and read conflict-free), + norms + L2E*beta.
// Physical 16B chunk pc within a row holds logical chunk lc where
// pc = (h<<3) | ((lc&7) ^ (row&7)), h = lc>>3 (K-half preserved).
__global__ __launch_bounds__(256) void prep_kernel(
    const float* __restrict__ p, const float* __restrict__ p_star,
    const float* __restrict__ beta_p, const float* __restrict__ beta_ps,
    const int* __restrict__ nodes_ps, const int* __restrict__ nodes_p,
    _Float16* __restrict__ Ah, float* __restrict__ n2A, float* __restrict__ bA2,
    _Float16* __restrict__ Bh, float* __restrict__ n2B, float* __restrict__ bB2)
{
    const int bx = blockIdx.x;
    const int g = threadIdx.x & 31;
    const int r8 = threadIdx.x >> 5;
    const bool isA = bx < 2048;
    const int row = (isA ? bx : bx - 2048) * 8 + r8;
    const int id = isA ? nodes_ps[row] : nodes_p[row];
    const float* src = isA ? p_star : p;
    float4 v = ((const float4*)(src + (size_t)id * DIM))[g];
    half4_t o;
    o[0] = (_Float16)v.x; o[1] = (_Float16)v.y; o[2] = (_Float16)v.z; o[3] = (_Float16)v.w;
    const int h = g >> 4;                      // K-half
    const int pc = ((g >> 1) & 7) ^ (row & 7); // swizzled in-half chunk
    _Float16* dst = isA ? Ah : Bh;
    *(half4_t*)(dst + (size_t)row * DIM + (((h << 3) | pc) << 3) + (g & 1) * 4) = o;
    float nrm = v.x * v.x + v.y * v.y + v.z * v.z + v.w * v.w;
    #pragma unroll
    for (int m = 16; m >= 1; m >>= 1) nrm += __shfl_xor(nrm, m, 32);
    if (g == 0) {
        if (isA) { n2A[row] = nrm; bA2[row] = L2E * beta_ps[id]; }
        else     { n2B[row] = nrm; bB2[row] = L2E * beta_p[id]; }
    }
}

// map wrapped-triangle tile index -> (i0, j0, diag)
__device__ __forceinline__ void tile_of(int t, int& i0, int& j0, bool& diag) {
    const int by = t / 129;
    const int bx = t - by * 129;
    const int len = 128 - by;
    int ti, tj;
    if (bx < len) { ti = by; tj = by + bx; }
    else          { ti = 127 - by; tj = 127 - (bx - len); }
    i0 = ti << 7; j0 = tj << 7; diag = (ti == tj);
}

// Stage a full 128x128 fp16 tile pair into LDS linearly via global_load_lds
// width-16. 2048 chunks per array; 4 per thread per array.
#define STAGE(I0, J0)                                                              \
    {                                                                              \
        _Pragma("unroll")                                                          \
        for (int u = 0; u < 4; ++u) {                                              \
            const int cidx = u * 512 + tid;                                        \
            const int row = cidx >> 4, cc = cidx & 15;                             \
            const int ldsoff = (u * 512 + w * 64) * 16;                            \
            __builtin_amdgcn_global_load_lds(                                      \
                (const __attribute__((address_space(1))) void*)(gA +               \
                    (((size_t)((I0) + row)) << 8) + (cc << 4)),                    \
                (__attribute__((address_space(3))) void*)(ldsA + ldsoff), 16, 0, 0); \
            __builtin_amdgcn_global_load_lds(                                      \
                (const __attribute__((address_space(1))) void*)(gB +               \
                    (((size_t)((J0) + row)) << 8) + (cc << 4)),                    \
                (__attribute__((address_space(3))) void*)(ldsB + ldsoff), 16, 0, 0); \
        }                                                                          \
    }

// Main: N_BLK persistent blocks of 512 threads. Per tile: compute (LDS reads)
// -> WAR barrier -> issue next tile's async stage -> link edges + epilogue
// (covers staging latency) -> barrier -> next tile.
__global__ __launch_bounds__(512, 4) void main_kernel(
    const _Float16* __restrict__ Ag, const _Float16* __restrict__ Bg,
    const float* __restrict__ n2A, const float* __restrict__ n2B,
    const float* __restrict__ bA2, const float* __restrict__ bB2,
    const int* __restrict__ edges,
    const float* __restrict__ beta_p, const float* __restrict__ beta_ps,
    const float* __restrict__ pf, const float* __restrict__ psf,
    float* __restrict__ pgemm)
{
    __shared__ __align__(16) _Float16 As[128 * 128];  // 32 KiB, swizzled rows
    __shared__ __align__(16) _Float16 Bs[128 * 128];  // 32 KiB
    __shared__ float smr[8];

    const int b = blockIdx.x;
    const int tid = threadIdx.x;
    const int lane = tid & 63;
    const int w = tid >> 6;       // 0..7
    const int wm = w & 3;         // 32-row quarter
    const int wn = w >> 2;        // 64-col half
    const int quad = lane >> 4;
    const int lr = lane & 15;
    const int k7 = lr & 7;        // read-side swizzle key (== row&7 of frag rows)

    auto* ldsA = (__attribute__((address_space(3))) char*)As;
    auto* ldsB = (__attribute__((address_space(3))) char*)Bs;
    const auto* gA = (const __attribute__((address_space(1))) char*)Ag;
    const auto* gB = (const __attribute__((address_space(1))) char*)Bg;

    float lsum = 0.f;

    int t = b;
    int i0, j0; bool diag;
    tile_of(t, i0, j0, diag);
    STAGE(i0, j0)
    __syncthreads();   // prologue tile ready

    for (;;) {
        // wave class on diagonal tiles: rows [wm*32,+32) vs cols [wn*64,+64)
        int cls = 0;  // 0=free (all j>i), 1=masked, 2=dead
        if (diag) cls = (wn == 0) ? (wm >= 2 ? 2 : 1) : (wm >= 2 ? 1 : 0);

        f32x4 acc[2][4] = {};
        if (cls != 2) {
            #pragma unroll
            for (int ks = 0; ks < 4; ++ks) {
                const int lc = ks * 4 + quad;                    // logical chunk 0..15
                const int pcx = ((lc & 8) | ((lc & 7) ^ k7)) << 3;
                half8 af[2], bf[4];
                #pragma unroll
                for (int u = 0; u < 2; ++u)
                    af[u] = *(const half8*)&As[(wm * 32 + u * 16 + lr) * 128 + pcx];
                #pragma unroll
                for (int v = 0; v < 4; ++v)
                    bf[v] = *(const half8*)&Bs[(wn * 64 + v * 16 + lr) * 128 + pcx];
                #pragma unroll
                for (int mi = 0; mi < 2; ++mi)
                    #pragma unroll
                    for (int ni = 0; ni < 4; ++ni)
                        acc[mi][ni] = __builtin_amdgcn_mfma_f32_16x16x32_f16(
                            af[mi], bf[ni], acc[mi][ni], 0, 0, 0);
            }
        }

        const int ilo = i0 + wm * 32, jlo = j0 + wn * 64;
        const int tcur = t;
        __syncthreads();                 // WAR: all LDS reads of this tile done

        t += N_BLK;
        const bool more = (t < NB_TILE);
        if (more) {
            tile_of(t, i0, j0, diag);
            STAGE(i0, j0)                // async; lands while we do link+epilogue
        }

        // ---- link edges of tile tcur: fp32, exact reference math ----
        #pragma unroll
        for (int tt = 0; tt < 2; ++tt) {
            int e = tcur * 64 + w * 8 + quad * 2 + tt;
            if (e < N_EDGES) {
                int e0 = edges[e];
                int e1 = edges[N_EDGES + e];
                const float* ar = pf + (size_t)e0 * DIM + lr * 8;
                const float* br = psf + (size_t)e1 * DIM + lr * 8;
                f32x4 a0 = *(const f32x4*)ar;   f32x4 a1 = *(const f32x4*)(ar + 4);
                f32x4 b0 = *(const f32x4*)br;   f32x4 b1 = *(const f32x4*)(br + 4);
                float eb2 = (lr == 0) ? (beta_ps[e0] + beta_p[e1]) : 0.f;
                float s = 0.f;
                #pragma unroll
                for (int k = 0; k < 4; ++k) { float d = a0[k] - b0[k] + EPS; s = fmaf(d, d, s); }
                #pragma unroll
                for (int k = 0; k < 4; ++k) { float d = a1[k] - b1[k] + EPS; s = fmaf(d, d, s); }
                #pragma unroll
                for (int m = 8; m >= 1; m >>= 1) s += __shfl_xor(s, m, 16);
                if (lr == 0) lsum -= eb2 - fast_sqrtf(s);
            }
        }

        // ---- epilogue (covers next tile's staging latency) ----
        if (cls != 2) {
            f32x4 n2i[2], bi[2];
            #pragma unroll
            for (int mi = 0; mi < 2; ++mi) {
                n2i[mi] = *(const f32x4*)&n2A[ilo + mi * 16 + quad * 4];
                bi[mi]  = *(const f32x4*)&bA2[ilo + mi * 16 + quad * 4];
            }
            float n2j[4], bj[4];
            #pragma unroll
            for (int ni = 0; ni < 4; ++ni) {
                n2j[ni] = n2B[jlo + ni * 16 + lr];
                bj[ni]  = bB2[jlo + ni * 16 + lr];
            }

            // C/D layout: col = lane&15, row = quad*4 + reg
            if (cls == 0) {
                #pragma unroll
                for (int mi = 0; mi < 2; ++mi)
                    #pragma unroll
                    for (int ni = 0; ni < 4; ++ni) {
                        f32x4 d = acc[mi][ni];
                        #pragma unroll
                        for (int r = 0; r < 4; ++r) {
                            float tt = n2i[mi][r] + n2j[ni];
                            float sq = fmaxf(fmaf(d[r], -2.f, tt), 0.f);
                            float arg = fmaf(fast_sqrtf(sq), -L2E, bi[mi][r] + bj[ni]);
                            lsum += fast_exp2f(arg);
                        }
                    }
            } else {
                #pragma unroll
                for (int mi = 0; mi < 2; ++mi)
                    #pragma unroll
                    for (int ni = 0; ni < 4; ++ni) {
                        f32x4 d = acc[mi][ni];
                        #pragma unroll
                        for (int r = 0; r < 4; ++r) {
                            int ig = ilo + mi * 16 + quad * 4 + r;
                            int jg = jlo + ni * 16 + lr;
                            float tt = n2i[mi][r] + n2j[ni];
                            float sq = fmaxf(fmaf(d[r], -2.f, tt), 0.f);
                            float arg = fmaf(fast_sqrtf(sq), -L2E, bi[mi][r] + bj[ni]);
                            float ex = fast_exp2f(arg);
                            if (jg > ig) lsum += ex;
                        }
                    }
            }
        }

        if (!more) break;
        __syncthreads();                 // staged tile ready (vmcnt drained)
    }

    #pragma unroll
    for (int m = 32; m >= 1; m >>= 1) lsum += __shfl_xor(lsum, m, 64);
    if (lane == 0) smr[w] = lsum;
    __syncthreads();
    if (tid == 0) {
        float s = 0.f;
        #pragma unroll
        for (int i = 0; i < 8; ++i) s += smr[i];
        pgemm[b] = s;
    }
}

// single-block final reduction over N_BLK partials
__global__ __launch_bounds__(1024) void reduce_kernel(
    const float* __restrict__ pg, float* __restrict__ out)
{
    float s = 0.f;
    for (int k = threadIdx.x; k < N_BLK; k += 1024) s += pg[k];
    #pragma unroll
    for (int m = 32; m >= 1; m >>= 1) s += __shfl_xor(s, m, 64);
    __shared__ float sm[16];
    if ((threadIdx.x & 63) == 0) sm[threadIdx.x >> 6] = s;
    __syncthreads();
    if (threadIdx.x == 0) {
        float t = 0.f;
        #pragma unroll
        for (int i = 0; i < 16; ++i) t += sm[i];
        out[0] = t;
    }
}

extern "C" void kernel_launch(void* const* d_in, const int* in_sizes, int n_in,
                              void* d_out, int out_size, void* d_ws, size_t ws_size,
                              hipStream_t stream) {
    const int* edges = (const int*)d_in[0];
    const int* nodes_p_star = (const int*)d_in[1];
    const int* nodes_p = (const int*)d_in[2];
    const float* beta_p = (const float*)d_in[3];
    const float* beta_p_star = (const float*)d_in[4];
    const float* p = (const float*)d_in[5];
    const float* p_star = (const float*)d_in[6];

    char* ws = (char*)d_ws;
    float* pgemm = (float*)(ws + OFF_PGEMM);
    _Float16* psh = (_Float16*)(ws + OFF_PSH);
    _Float16* pph = (_Float16*)(ws + OFF_PPH);
    float* n2s = (float*)(ws + OFF_N2S);
    float* n2p = (float*)(ws + OFF_N2P);
    float* bps2 = (float*)(ws + OFF_BPS);
    float* bp2 = (float*)(ws + OFF_BP);

    prep_kernel<<<4096, 256, 0, stream>>>(
        p, p_star, beta_p, beta_p_star, nodes_p_star, nodes_p,
        psh, n2s, bps2, pph, n2p, bp2);

    main_kernel<<<N_BLK, 512, 0, stream>>>(
        psh, pph, n2s, n2p, bps2, bp2,
        edges, beta_p, beta_p_star, p, p_star,
        pgemm);

    reduce_kernel<<<1, 1024, 0, stream>>>(pgemm, (float*)d_out);
}